// Round 1
// baseline (2803.738 us; speedup 1.0000x reference)
//
#include <hip/hip_runtime.h>
#include <hip/hip_bf16.h>
#include <math.h>

// ---------------------------------------------------------------------------
// Problem constants (KAE forward, full batch)
// ---------------------------------------------------------------------------
#define NN   3072
#define NIN  784
#define E1D  500
#define E2D  500
#define E3D  2000
#define NZD  10
#define NCD  10

// ---------------------------------------------------------------------------
// bf16x3 split-MFMA GEMM: C = A(MxK) * B + bias   (fp32 in/out)
//   Each fp32 operand is split into hi=bf16(x), lo=bf16(x-hi); the product is
//   computed as Ahi*Bhi + Ahi*Blo + Alo*Bhi on the matrix cores with fp32
//   accumulation (~1e-5 relative error vs fp32, ~MFMA_rate/3 useful FLOPs).
//   TRANSB=false: B is KxN row-major
//   TRANSB=true : B is NxK row-major (computes A * B^T) -- used for h @ h^T
// 128x128 tile, BK=32, 256 threads (4 waves, 2x2 of 64x64 wave-tiles).
// ---------------------------------------------------------------------------
#define BM 128
#define BN 128
#define BK 32
#define LDK 40   // padded LDS row length in ushorts (80 B) -> bank spread

typedef __attribute__((ext_vector_type(4))) float  f32x4;
typedef __attribute__((ext_vector_type(8))) __bf16 bf16x8;

__device__ __forceinline__ void split4(const float4 v, ushort4& h, ushort4& l)
{
    __bf16 hx = (__bf16)v.x, hy = (__bf16)v.y, hz = (__bf16)v.z, hw = (__bf16)v.w;
    h.x = __builtin_bit_cast(unsigned short, hx);
    h.y = __builtin_bit_cast(unsigned short, hy);
    h.z = __builtin_bit_cast(unsigned short, hz);
    h.w = __builtin_bit_cast(unsigned short, hw);
    l.x = __builtin_bit_cast(unsigned short, (__bf16)(v.x - (float)hx));
    l.y = __builtin_bit_cast(unsigned short, (__bf16)(v.y - (float)hy));
    l.z = __builtin_bit_cast(unsigned short, (__bf16)(v.z - (float)hz));
    l.w = __builtin_bit_cast(unsigned short, (__bf16)(v.w - (float)hw));
}

template <bool TRANSB>
__global__ __launch_bounds__(256)
void mfma_gemm(const float* __restrict__ A, const float* __restrict__ B,
               const float* __restrict__ bias, float* __restrict__ C,
               int M, int N, int K)
{
    __shared__ unsigned short Ah[BM][LDK];
    __shared__ unsigned short Al[BM][LDK];
    __shared__ unsigned short Bh[BN][LDK];
    __shared__ unsigned short Bl[BN][LDK];

    const int tid  = threadIdx.x;
    const int bm   = blockIdx.y * BM;
    const int bn   = blockIdx.x * BN;
    const int lane = tid & 63;
    const int wid  = tid >> 6;
    const int wm   = (wid >> 1) * 64;   // wave row offset in tile
    const int wn   = (wid & 1) * 64;    // wave col offset in tile
    const int lr   = lane & 15;         // fragment row/col index
    const int g    = lane >> 4;         // k-group (0..3), 8 bf16 each

    const f32x4 fzero = {0.f, 0.f, 0.f, 0.f};
    f32x4 acc[4][4];
#pragma unroll
    for (int i = 0; i < 4; ++i)
#pragma unroll
        for (int j = 0; j < 4; ++j) acc[i][j] = fzero;

    const bool k4 = (K & 3) == 0;       // float4-aligned fast path

    for (int k0 = 0; k0 < K; k0 += BK) {
        // ---- stage A tile: rows bm..bm+127, k0..k0+31 -> (hi,lo) bf16 ----
#pragma unroll
        for (int p = 0; p < 4; ++p) {
            int idx = tid + p * 256;        // 0..1023
            int row = idx >> 3;             // 0..127
            int kq  = (idx & 7) << 2;       // 0,4,..,28
            int gm = bm + row, gk = k0 + kq;
            float4 v = make_float4(0.f, 0.f, 0.f, 0.f);
            if (gm < M && gk < K) {
                const float* ap = A + (size_t)gm * K + gk;
                if (k4) {
                    v = *(const float4*)ap;
                } else {
                    v.x = ap[0];
                    if (gk + 1 < K) v.y = ap[1];
                    if (gk + 2 < K) v.z = ap[2];
                    if (gk + 3 < K) v.w = ap[3];
                }
            }
            ushort4 h, l; split4(v, h, l);
            *(ushort4*)&Ah[row][kq] = h;
            *(ushort4*)&Al[row][kq] = l;
        }
        // ---- stage B tile ----
        if (TRANSB) {
            // B is [N][K] row-major: identical staging to A
#pragma unroll
            for (int p = 0; p < 4; ++p) {
                int idx = tid + p * 256;
                int row = idx >> 3;
                int kq  = (idx & 7) << 2;
                int gn = bn + row, gk = k0 + kq;
                float4 v = make_float4(0.f, 0.f, 0.f, 0.f);
                if (gn < N && gk < K) {
                    const float* bp = B + (size_t)gn * K + gk;
                    if (k4) {
                        v = *(const float4*)bp;
                    } else {
                        v.x = bp[0];
                        if (gk + 1 < K) v.y = bp[1];
                        if (gk + 2 < K) v.z = bp[2];
                        if (gk + 3 < K) v.w = bp[3];
                    }
                }
                ushort4 h, l; split4(v, h, l);
                *(ushort4*)&Bh[row][kq] = h;
                *(ushort4*)&Bl[row][kq] = l;
            }
        } else {
            // B is [K][N]: transpose into Bs[n][k].
            // Thread t handles column n=t&127 for 16 k's (coalesced across lanes).
            int n    = tid & 127;
            int half = (tid >> 7) << 4;     // 0 or 16
            int gn   = bn + n;
            float vv[16];
#pragma unroll
            for (int kk = 0; kk < 16; ++kk) {
                int gk = k0 + half + kk;
                vv[kk] = (gn < N && gk < K) ? B[(size_t)gk * N + gn] : 0.f;
            }
#pragma unroll
            for (int q = 0; q < 4; ++q) {
                float4 v = make_float4(vv[q*4+0], vv[q*4+1], vv[q*4+2], vv[q*4+3]);
                ushort4 h, l; split4(v, h, l);
                *(ushort4*)&Bh[n][half + q*4] = h;
                *(ushort4*)&Bl[n][half + q*4] = l;
            }
        }
        __syncthreads();

        // ---- fragments + MFMA (A/B packed with identical lane->(row,k) map:
        //      row/col = lane&15, k = 8*(lane>>4)+i; consistent-bijection safe)
        bf16x8 fah[4], fal[4], fbh[4], fbl[4];
#pragma unroll
        for (int t = 0; t < 4; ++t) {
            fah[t] = *reinterpret_cast<const bf16x8*>(&Ah[wm + t*16 + lr][g*8]);
            fal[t] = *reinterpret_cast<const bf16x8*>(&Al[wm + t*16 + lr][g*8]);
            fbh[t] = *reinterpret_cast<const bf16x8*>(&Bh[wn + t*16 + lr][g*8]);
            fbl[t] = *reinterpret_cast<const bf16x8*>(&Bl[wn + t*16 + lr][g*8]);
        }
#pragma unroll
        for (int mt = 0; mt < 4; ++mt)
#pragma unroll
            for (int nt = 0; nt < 4; ++nt) {
                acc[mt][nt] = __builtin_amdgcn_mfma_f32_16x16x32_bf16(
                                  fah[mt], fbh[nt], acc[mt][nt], 0, 0, 0);
                acc[mt][nt] = __builtin_amdgcn_mfma_f32_16x16x32_bf16(
                                  fah[mt], fbl[nt], acc[mt][nt], 0, 0, 0);
                acc[mt][nt] = __builtin_amdgcn_mfma_f32_16x16x32_bf16(
                                  fal[mt], fbh[nt], acc[mt][nt], 0, 0, 0);
            }
        __syncthreads();
    }

    // ---- epilogue: C/D layout (HW-verified): col=lane&15, row=(lane>>4)*4+r
#pragma unroll
    for (int mt = 0; mt < 4; ++mt)
#pragma unroll
        for (int nt = 0; nt < 4; ++nt) {
            int gn = bn + wn + nt*16 + lr;
            if (gn >= N) continue;
            float bv = (bias != nullptr) ? bias[gn] : 0.f;
#pragma unroll
            for (int r = 0; r < 4; ++r) {
                int gm = bm + wm + mt*16 + (g << 2) + r;
                if (gm < M) C[(size_t)gm * N + gn] = acc[mt][nt][r] + bv;
            }
        }
}

// ---------------------------------------------------------------------------
// s[i] = lin[i][i]
// ---------------------------------------------------------------------------
__global__ void diag_kernel(const float* __restrict__ lin, float* __restrict__ s, int N)
{
    int i = blockIdx.x * blockDim.x + threadIdx.x;
    if (i < N) s[i] = lin[(size_t)i * N + i];
}

// ---------------------------------------------------------------------------
// rowsum[i] = sum_j exp(-0.5*sq_ij) * (i != j)
// ---------------------------------------------------------------------------
__global__ __launch_bounds__(256)
void rowsumA_kernel(const float* __restrict__ lin, const float* __restrict__ s,
                    float* __restrict__ rowsum, int N)
{
    int i = blockIdx.x;
    float si = s[i];
    float acc = 0.f;
    for (int j = threadIdx.x; j < N; j += 256) {
        float l  = lin[(size_t)i * N + j];
        float sq = fmaxf(si + s[j] - 2.f * l, 0.f);
        float a  = expf(-0.5f * sq);
        acc += (j == i) ? 0.f : a;
    }
    __shared__ float red[256];
    red[threadIdx.x] = acc;
    __syncthreads();
    for (int o = 128; o > 0; o >>= 1) {
        if (threadIdx.x < o) red[threadIdx.x] += red[threadIdx.x + o];
        __syncthreads();
    }
    if (threadIdx.x == 0) rowsum[i] = red[0];
}

// ---------------------------------------------------------------------------
// In-place: lin -> e*lin + f*studentT + g*poly + h*graph
// ---------------------------------------------------------------------------
__global__ __launch_bounds__(256)
void combine_kernel(float* __restrict__ lin_io,
                    const float* __restrict__ s, const float* __restrict__ rowsum,
                    const float* __restrict__ ce, const float* __restrict__ cf,
                    const float* __restrict__ cg, const float* __restrict__ ch,
                    int N)
{
    int j = blockIdx.x * 256 + threadIdx.x;
    int i = blockIdx.y;
    size_t idx = (size_t)i * N + j;
    float l   = lin_io[idx];
    float sq  = fmaxf(s[i] + s[j] - 2.f * l, 0.f);
    float tk  = 1.f / (1.f + sq);
    float lp1 = l + 1.f;
    float pk  = lp1 * lp1;
    float a   = (i == j) ? 0.f : expf(-0.5f * sq);
    float di  = 1.f / sqrtf(rowsum[i] + 1e-12f);
    float dj  = 1.f / sqrtf(rowsum[j] + 1e-12f);
    float gk  = a * di * dj;
    lin_io[idx] = ce[idx] * l + cf[idx] * tk + cg[idx] * pk + ch[idx] * gk;
}

// ---------------------------------------------------------------------------
// k = a*kh1 + b*kh2 + c*kh3 + d*kz
// ---------------------------------------------------------------------------
__global__ __launch_bounds__(256)
void kcombine_kernel(const float4* __restrict__ kh1, const float4* __restrict__ kh2,
                     const float4* __restrict__ kh3, const float4* __restrict__ kz,
                     const float4* __restrict__ ca, const float4* __restrict__ cb,
                     const float4* __restrict__ cc, const float4* __restrict__ cd,
                     float4* __restrict__ out, int n4)
{
    int idx = blockIdx.x * 256 + threadIdx.x;
    if (idx >= n4) return;
    float4 A = ca[idx], B = cb[idx], C = cc[idx], D = cd[idx];
    float4 K1 = kh1[idx], K2 = kh2[idx], K3 = kh3[idx], KZ = kz[idx];
    float4 r;
    r.x = A.x * K1.x + B.x * K2.x + C.x * K3.x + D.x * KZ.x;
    r.y = A.y * K1.y + B.y * K2.y + C.y * K3.y + D.y * KZ.y;
    r.z = A.z * K1.z + B.z * K2.z + C.z * K3.z + D.z * KZ.z;
    r.w = A.w * K1.w + B.w * K2.w + C.w * K3.w + D.w * KZ.w;
    out[idx] = r;
}

// ---------------------------------------------------------------------------
// q[i][c][j] = k[i][j] - cluster[c][j]
// ---------------------------------------------------------------------------
__global__ __launch_bounds__(256)
void q_kernel(const float4* __restrict__ k, const float4* __restrict__ cl,
              float4* __restrict__ q, int N, int NC)
{
    int i  = blockIdx.y;
    int f4 = blockIdx.x * 256 + threadIdx.x;
    int n4 = N / 4;
    int c  = f4 / n4;
    int j4 = f4 - c * n4;
    float4 kv = k[(size_t)i * n4 + j4];
    float4 cv = cl[(size_t)c * n4 + j4];
    float4 r;
    r.x = kv.x - cv.x; r.y = kv.y - cv.y; r.z = kv.z - cv.z; r.w = kv.w - cv.w;
    q[((size_t)i * NC + c) * n4 + j4] = r;
}

// ---------------------------------------------------------------------------
// Launch
// ---------------------------------------------------------------------------
extern "C" void kernel_launch(void* const* d_in, const int* in_sizes, int n_in,
                              void* d_out, int out_size, void* d_ws, size_t ws_size,
                              hipStream_t stream)
{
    const int N = NN;
    const float* x     = (const float*)d_in[0];
    const float* Wenc1 = (const float*)d_in[1];
    const float* benc1 = (const float*)d_in[2];
    const float* Wenc2 = (const float*)d_in[3];
    const float* benc2 = (const float*)d_in[4];
    const float* Wenc3 = (const float*)d_in[5];
    const float* benc3 = (const float*)d_in[6];
    const float* Wz    = (const float*)d_in[7];
    const float* bz    = (const float*)d_in[8];
    const float* Wk1   = (const float*)d_in[9];
    const float* bk1   = (const float*)d_in[10];
    const float* Wk2   = (const float*)d_in[11];
    const float* bk2   = (const float*)d_in[12];
    const float* Wk3   = (const float*)d_in[13];
    const float* bk3   = (const float*)d_in[14];
    const float* Wk4   = (const float*)d_in[15];
    const float* bk4   = (const float*)d_in[16];
    const float* c_a  = (const float*)d_in[17];
    const float* c_b  = (const float*)d_in[18];
    const float* c_c  = (const float*)d_in[19];
    const float* c_d  = (const float*)d_in[20];
    const float* c_e  = (const float*)d_in[21];
    const float* c_f  = (const float*)d_in[22];
    const float* c_g  = (const float*)d_in[23];
    const float* c_h  = (const float*)d_in[24];
    const float* c_e1 = (const float*)d_in[25];
    const float* c_f1 = (const float*)d_in[26];
    const float* c_g1 = (const float*)d_in[27];
    const float* c_h1 = (const float*)d_in[28];
    const float* c_e2 = (const float*)d_in[29];
    const float* c_f2 = (const float*)d_in[30];
    const float* c_g2 = (const float*)d_in[31];
    const float* c_h2 = (const float*)d_in[32];
    const float* c_e3 = (const float*)d_in[33];
    const float* c_f3 = (const float*)d_in[34];
    const float* c_g3 = (const float*)d_in[35];
    const float* c_h3 = (const float*)d_in[36];
    const float* cluster = (const float*)d_in[37];

    float* out   = (float*)d_out;
    float* xbar  = out + 0;          // 3072*784
    float* k_out = out + 2408448;    // 3072*3072
    float* z_out = out + 11845632;   // 3072*10
    float* h1    = out + 11876352;   // 3072*500
    float* h2    = out + 13412352;   // 3072*500
    float* h3    = out + 14948352;   // 3072*2000
    float* q_out = out + 21092352;   // 3072*10*3072
    float* k22   = out + 115464192;  // 3072*500
    float* k33   = out + 117000192;  // 3072*500
    float* kh1   = out + 118536192;  // 3072*3072
    float* kh2   = out + 127973376;  // 3072*3072
    float* kh3   = out + 137410560;  // 3072*3072
    float* kz    = out + 146847744;  // 3072*3072

    float* ws = (float*)d_ws;
    float* k1 = ws;                  // 3072*2000
    float* s1 = ws + 6144000;
    float* s2 = s1 + N;
    float* s3 = s2 + N;
    float* sz = s3 + N;
    float* r1 = sz + N;
    float* r2 = r1 + N;
    float* r3 = r2 + N;
    float* rz = r3 + N;

    dim3 blk(256);
    auto gg = [](int m, int n) { return dim3((n + BN - 1) / BN, (m + BM - 1) / BM); };
    dim3 rowgrid(N);
    dim3 cgrid(N / 256, N);
    dim3 dgrid((N + 255) / 256);

    // ===== encoder layer 1 =====
    mfma_gemm<false><<<gg(N, E1D), blk, 0, stream>>>(x, Wenc1, benc1, h1, N, E1D, NIN);
    mfma_gemm<true ><<<gg(N, N),   blk, 0, stream>>>(h1, h1, nullptr, kh1, N, N, E1D);
    diag_kernel<<<dgrid, blk, 0, stream>>>(kh1, s1, N);
    rowsumA_kernel<<<rowgrid, blk, 0, stream>>>(kh1, s1, r1, N);
    combine_kernel<<<cgrid, blk, 0, stream>>>(kh1, s1, r1, c_e1, c_f1, c_g1, c_h1, N);

    // ===== encoder layer 2 =====
    mfma_gemm<false><<<gg(N, E2D), blk, 0, stream>>>(h1, Wenc2, benc2, h2, N, E2D, E1D);
    mfma_gemm<true ><<<gg(N, N),   blk, 0, stream>>>(h2, h2, nullptr, kh2, N, N, E2D);
    diag_kernel<<<dgrid, blk, 0, stream>>>(kh2, s2, N);
    rowsumA_kernel<<<rowgrid, blk, 0, stream>>>(kh2, s2, r2, N);
    combine_kernel<<<cgrid, blk, 0, stream>>>(kh2, s2, r2, c_e2, c_f2, c_g2, c_h2, N);

    // ===== encoder layer 3 =====
    mfma_gemm<false><<<gg(N, E3D), blk, 0, stream>>>(h2, Wenc3, benc3, h3, N, E3D, E2D);
    mfma_gemm<true ><<<gg(N, N),   blk, 0, stream>>>(h3, h3, nullptr, kh3, N, N, E3D);
    diag_kernel<<<dgrid, blk, 0, stream>>>(kh3, s3, N);
    rowsumA_kernel<<<rowgrid, blk, 0, stream>>>(kh3, s3, r3, N);
    combine_kernel<<<cgrid, blk, 0, stream>>>(kh3, s3, r3, c_e3, c_f3, c_g3, c_h3, N);

    // ===== latent z =====
    mfma_gemm<false><<<gg(N, NZD), blk, 0, stream>>>(h3, Wz, bz, z_out, N, NZD, E3D);
    mfma_gemm<true ><<<gg(N, N),   blk, 0, stream>>>(z_out, z_out, nullptr, kz, N, N, NZD);
    diag_kernel<<<dgrid, blk, 0, stream>>>(kz, sz, N);
    rowsumA_kernel<<<rowgrid, blk, 0, stream>>>(kz, sz, rz, N);
    combine_kernel<<<cgrid, blk, 0, stream>>>(kz, sz, rz, c_e, c_f, c_g, c_h, N);

    // ===== k = a*kh1 + b*kh2 + c*kh3 + d*kz =====
    {
        int n4 = N * N / 4;
        kcombine_kernel<<<dim3((n4 + 255) / 256), blk, 0, stream>>>(
            (const float4*)kh1, (const float4*)kh2, (const float4*)kh3, (const float4*)kz,
            (const float4*)c_a, (const float4*)c_b, (const float4*)c_c, (const float4*)c_d,
            (float4*)k_out, n4);
    }

    // ===== decoder chain =====
    mfma_gemm<false><<<gg(N, 2000), blk, 0, stream>>>(k_out, Wk1, bk1, k1, N, 2000, N);
    mfma_gemm<false><<<gg(N, 500),  blk, 0, stream>>>(k1, Wk2, bk2, k22, N, 500, 2000);
    mfma_gemm<false><<<gg(N, 500),  blk, 0, stream>>>(k22, Wk3, bk3, k33, N, 500, 500);
    mfma_gemm<false><<<gg(N, NIN),  blk, 0, stream>>>(k33, Wk4, bk4, xbar, N, NIN, 500);

    // ===== q = k[:,None,:] - cluster[None,:,:] =====
    {
        int per_i = NCD * N / 4;
        q_kernel<<<dim3(per_i / 256, N), blk, 0, stream>>>(
            (const float4*)k_out, (const float4*)cluster, (float4*)q_out, N, NCD);
    }
}

// Round 2
// 2241.668 us; speedup vs baseline: 1.2507x; 1.2507x over previous
//
#include <hip/hip_runtime.h>
#include <hip/hip_bf16.h>
#include <math.h>

// ---------------------------------------------------------------------------
// Problem constants (KAE forward, full batch)
// ---------------------------------------------------------------------------
#define NN   3072
#define NIN  784
#define E1D  500
#define E2D  500
#define E3D  2000
#define NZD  10
#define NCD  10

// GEMM tile config: 128x128 tile, BK=32, 256 threads (4 waves as 2x2 of 64x64)
#define BM 128
#define BN 128
#define BK 32

typedef __attribute__((ext_vector_type(4))) float  f32x4;
typedef __attribute__((ext_vector_type(8))) __bf16 bf16x8;

// ---------------------------------------------------------------------------
// helpers
// ---------------------------------------------------------------------------
__device__ __forceinline__ void split4(const float4 v, ushort4& h, ushort4& l)
{
    __bf16 hx = (__bf16)v.x, hy = (__bf16)v.y, hz = (__bf16)v.z, hw = (__bf16)v.w;
    h.x = __builtin_bit_cast(unsigned short, hx);
    h.y = __builtin_bit_cast(unsigned short, hy);
    h.z = __builtin_bit_cast(unsigned short, hz);
    h.w = __builtin_bit_cast(unsigned short, hw);
    l.x = __builtin_bit_cast(unsigned short, (__bf16)(v.x - (float)hx));
    l.y = __builtin_bit_cast(unsigned short, (__bf16)(v.y - (float)hy));
    l.z = __builtin_bit_cast(unsigned short, (__bf16)(v.z - (float)hz));
    l.w = __builtin_bit_cast(unsigned short, (__bf16)(v.w - (float)hw));
}

__device__ __forceinline__ void split1(float v, unsigned short& h, unsigned short& l)
{
    __bf16 hh = (__bf16)v;
    h = __builtin_bit_cast(unsigned short, hh);
    l = __builtin_bit_cast(unsigned short, (__bf16)(v - (float)hh));
}

// async global -> LDS, 16 bytes per lane (dest = wave-uniform base + lane*16)
__device__ __forceinline__ void gl16(const void* g, void* l)
{
    __builtin_amdgcn_global_load_lds(
        (const __attribute__((address_space(1))) void*)g,
        (__attribute__((address_space(3))) void*)l,
        16, 0, 0);
}

// ---------------------------------------------------------------------------
// bf16x3 split GEMM (m97-style structure): C = A * B^T (+bias)
//   A: hi/lo bf16 [M][Kp]   (M = 3072 always, multiple of BM)
//   B: hi/lo bf16 [Rp][Kp]  (rows padded to multiple of BN, pad rows zero)
//   Kp multiple of BK, pad cols zero.
//   C fp32 [M][N] (optional), plus optional hi/lo split output [M][CKp]
//   (pad cols of split output zero-filled; grid covers N rounded to BN >= CKp)
// ---------------------------------------------------------------------------
template <bool SPLIT_OUT>
__global__ __launch_bounds__(256)
void gemm3(const unsigned short* __restrict__ Ah, const unsigned short* __restrict__ Al,
           const unsigned short* __restrict__ Bh, const unsigned short* __restrict__ Bl,
           const float* __restrict__ bias, float* __restrict__ C,
           unsigned short* __restrict__ Ch, unsigned short* __restrict__ Cl, int CKp,
           int M, int N, int Kp)
{
    __shared__ unsigned short ldsAh[BM * BK];
    __shared__ unsigned short ldsAl[BM * BK];
    __shared__ unsigned short ldsBh[BN * BK];
    __shared__ unsigned short ldsBl[BN * BK];

    const int tid  = threadIdx.x;
    const int lane = tid & 63;
    const int wid  = tid >> 6;
    const int bm   = blockIdx.y * BM;
    const int bn   = blockIdx.x * BN;
    const int wm   = (wid >> 1) * 64;
    const int wn   = (wid & 1) * 64;
    const int lr   = lane & 15;
    const int g    = lane >> 4;

    f32x4 acc[4][4];
#pragma unroll
    for (int i = 0; i < 4; ++i)
#pragma unroll
        for (int j = 0; j < 4; ++j) acc[i][j] = (f32x4){0.f, 0.f, 0.f, 0.f};

    // staging: tile = 128 rows x 32 cols bf16 = 8192 B = 512 chunks of 16 B.
    // chunk c: row = c>>2, q = c&3 (16B = 8 bf16). Wave w issue p covers
    // chunks [p*256 + w*64, +64): LDS base wave-uniform, lane adds its 16 B.
    auto stage = [&](const unsigned short* src, int row0, unsigned short* ldst) {
#pragma unroll
        for (int p = 0; p < 2; ++p) {
            int cb  = p * 256 + wid * 64;        // wave-uniform chunk base
            int c   = cb + lane;
            int row = c >> 2, q = c & 3;
            const unsigned short* gp = src + (size_t)(row0 + row) * Kp + q * 8;
            gl16((const void*)gp, (void*)(ldst + cb * 8));
        }
    };

    for (int k0 = 0; k0 < Kp; k0 += BK) {
        stage(Ah + k0, bm, ldsAh);
        stage(Al + k0, bm, ldsAl);
        stage(Bh + k0, bn, ldsBh);
        stage(Bl + k0, bn, ldsBl);
        __syncthreads();

        bf16x8 fah[4], fal[4], fbh[4], fbl[4];
#pragma unroll
        for (int t = 0; t < 4; ++t) {
            fah[t] = *(const bf16x8*)&ldsAh[(wm + t*16 + lr) * BK + g * 8];
            fal[t] = *(const bf16x8*)&ldsAl[(wm + t*16 + lr) * BK + g * 8];
            fbh[t] = *(const bf16x8*)&ldsBh[(wn + t*16 + lr) * BK + g * 8];
            fbl[t] = *(const bf16x8*)&ldsBl[(wn + t*16 + lr) * BK + g * 8];
        }
#pragma unroll
        for (int mt = 0; mt < 4; ++mt)
#pragma unroll
            for (int nt = 0; nt < 4; ++nt) {
                acc[mt][nt] = __builtin_amdgcn_mfma_f32_16x16x32_bf16(
                                  fah[mt], fbh[nt], acc[mt][nt], 0, 0, 0);
                acc[mt][nt] = __builtin_amdgcn_mfma_f32_16x16x32_bf16(
                                  fah[mt], fbl[nt], acc[mt][nt], 0, 0, 0);
                acc[mt][nt] = __builtin_amdgcn_mfma_f32_16x16x32_bf16(
                                  fal[mt], fbh[nt], acc[mt][nt], 0, 0, 0);
            }
        __syncthreads();
    }

    // epilogue: C/D layout (HW-verified): col = lane&15, row = (lane>>4)*4 + r
#pragma unroll
    for (int mt = 0; mt < 4; ++mt) {
        int rbase = bm + wm + mt * 16 + g * 4;
#pragma unroll
        for (int nt = 0; nt < 4; ++nt) {
            int gn = bn + wn + nt * 16 + lr;
            bool innk = (gn < N);
            float bv = (bias != nullptr && innk) ? bias[gn] : 0.f;
#pragma unroll
            for (int r = 0; r < 4; ++r) {
                int row = rbase + r;
                if (row >= M) continue;
                float v = acc[mt][nt][r] + bv;
                if (C != nullptr && innk) C[(size_t)row * N + gn] = v;
                if (SPLIT_OUT) {
                    if (gn < CKp) {
                        float vv = innk ? v : 0.f;
                        unsigned short h, l; split1(vv, h, l);
                        Ch[(size_t)row * CKp + gn] = h;
                        Cl[(size_t)row * CKp + gn] = l;
                    }
                }
            }
        }
    }
}

// ---------------------------------------------------------------------------
// split fp32 [R][C] -> hi/lo bf16 [R][Cp] (pad cols zero)   (used for x)
// ---------------------------------------------------------------------------
__global__ __launch_bounds__(256)
void split_pad_kernel(const float* __restrict__ in,
                      unsigned short* __restrict__ oh, unsigned short* __restrict__ ol,
                      int R, int C, int Cp)
{
    int idx = blockIdx.x * 256 + threadIdx.x;
    if (idx >= R * Cp) return;
    int r = idx / Cp, c = idx - r * Cp;
    float v = (c < C) ? in[(size_t)r * C + c] : 0.f;
    unsigned short h, l; split1(v, h, l);
    oh[idx] = h; ol[idx] = l;
}

// ---------------------------------------------------------------------------
// split+transpose fp32 W[K][N] -> hi/lo bf16 Wt[Rp][Kp], Wt[n][k]=W[k][n]
// (pads zero). grid = (Rp/32, Kp/32), 256 threads.
// ---------------------------------------------------------------------------
__global__ __launch_bounds__(256)
void split_transpose_kernel(const float* __restrict__ in,
                            unsigned short* __restrict__ oh, unsigned short* __restrict__ ol,
                            int K, int N, int Kp)
{
    __shared__ float t[32][33];
    int nb = blockIdx.x * 32;
    int kb = blockIdx.y * 32;
    int tx = threadIdx.x & 31, ty = threadIdx.x >> 5;   // ty 0..7
#pragma unroll
    for (int i = 0; i < 4; ++i) {
        int k = kb + ty + i * 8, n = nb + tx;
        t[ty + i * 8][tx] = (k < K && n < N) ? in[(size_t)k * N + n] : 0.f;
    }
    __syncthreads();
#pragma unroll
    for (int i = 0; i < 4; ++i) {
        int n = nb + ty + i * 8, k = kb + tx;
        float v = t[tx][ty + i * 8];
        unsigned short h, l; split1(v, h, l);
        size_t o = (size_t)n * Kp + k;
        oh[o] = h; ol[o] = l;
    }
}

// ---------------------------------------------------------------------------
// s[i] = lin[i][i]
// ---------------------------------------------------------------------------
__global__ void diag_kernel(const float* __restrict__ lin, float* __restrict__ s, int N)
{
    int i = blockIdx.x * blockDim.x + threadIdx.x;
    if (i < N) s[i] = lin[(size_t)i * N + i];
}

// ---------------------------------------------------------------------------
// rowsum[i] = sum_j exp(-0.5*sq_ij) * (i != j)
// ---------------------------------------------------------------------------
__global__ __launch_bounds__(256)
void rowsumA_kernel(const float* __restrict__ lin, const float* __restrict__ s,
                    float* __restrict__ rowsum, int N)
{
    int i = blockIdx.x;
    float si = s[i];
    float acc = 0.f;
    for (int j = threadIdx.x; j < N; j += 256) {
        float l  = lin[(size_t)i * N + j];
        float sq = fmaxf(si + s[j] - 2.f * l, 0.f);
        float a  = expf(-0.5f * sq);
        acc += (j == i) ? 0.f : a;
    }
    __shared__ float red[256];
    red[threadIdx.x] = acc;
    __syncthreads();
    for (int o = 128; o > 0; o >>= 1) {
        if (threadIdx.x < o) red[threadIdx.x] += red[threadIdx.x + o];
        __syncthreads();
    }
    if (threadIdx.x == 0) rowsum[i] = red[0];
}

// ---------------------------------------------------------------------------
// In-place: lin -> e*lin + f*studentT + g*poly + h*graph
// ---------------------------------------------------------------------------
__global__ __launch_bounds__(256)
void combine_kernel(float* __restrict__ lin_io,
                    const float* __restrict__ s, const float* __restrict__ rowsum,
                    const float* __restrict__ ce, const float* __restrict__ cf,
                    const float* __restrict__ cg, const float* __restrict__ ch,
                    int N)
{
    int j = blockIdx.x * 256 + threadIdx.x;
    int i = blockIdx.y;
    size_t idx = (size_t)i * N + j;
    float l   = lin_io[idx];
    float sq  = fmaxf(s[i] + s[j] - 2.f * l, 0.f);
    float tk  = 1.f / (1.f + sq);
    float lp1 = l + 1.f;
    float pk  = lp1 * lp1;
    float a   = (i == j) ? 0.f : expf(-0.5f * sq);
    float di  = 1.f / sqrtf(rowsum[i] + 1e-12f);
    float dj  = 1.f / sqrtf(rowsum[j] + 1e-12f);
    float gk  = a * di * dj;
    lin_io[idx] = ce[idx] * l + cf[idx] * tk + cg[idx] * pk + ch[idx] * gk;
}

// ---------------------------------------------------------------------------
// k = a*kh1 + b*kh2 + c*kh3 + d*kz  (+ fused hi/lo split of k)
// ---------------------------------------------------------------------------
__global__ __launch_bounds__(256)
void kcombine_kernel(const float4* __restrict__ kh1, const float4* __restrict__ kh2,
                     const float4* __restrict__ kh3, const float4* __restrict__ kz,
                     const float4* __restrict__ ca, const float4* __restrict__ cb,
                     const float4* __restrict__ cc, const float4* __restrict__ cd,
                     float4* __restrict__ out,
                     ushort4* __restrict__ ksh, ushort4* __restrict__ ksl, int n4)
{
    int idx = blockIdx.x * 256 + threadIdx.x;
    if (idx >= n4) return;
    float4 A = ca[idx], B = cb[idx], C = cc[idx], D = cd[idx];
    float4 K1 = kh1[idx], K2 = kh2[idx], K3 = kh3[idx], KZ = kz[idx];
    float4 r;
    r.x = A.x * K1.x + B.x * K2.x + C.x * K3.x + D.x * KZ.x;
    r.y = A.y * K1.y + B.y * K2.y + C.y * K3.y + D.y * KZ.y;
    r.z = A.z * K1.z + B.z * K2.z + C.z * K3.z + D.z * KZ.z;
    r.w = A.w * K1.w + B.w * K2.w + C.w * K3.w + D.w * KZ.w;
    out[idx] = r;
    ushort4 h, l; split4(r, h, l);
    ksh[idx] = h; ksl[idx] = l;
}

// ---------------------------------------------------------------------------
// q[i][c][j] = k[i][j] - cluster[c][j]
// ---------------------------------------------------------------------------
__global__ __launch_bounds__(256)
void q_kernel(const float4* __restrict__ k, const float4* __restrict__ cl,
              float4* __restrict__ q, int N, int NC)
{
    int i  = blockIdx.y;
    int f4 = blockIdx.x * 256 + threadIdx.x;
    int n4 = N / 4;
    int c  = f4 / n4;
    int j4 = f4 - c * n4;
    float4 kv = k[(size_t)i * n4 + j4];
    float4 cv = cl[(size_t)c * n4 + j4];
    float4 r;
    r.x = kv.x - cv.x; r.y = kv.y - cv.y; r.z = kv.z - cv.z; r.w = kv.w - cv.w;
    q[((size_t)i * NC + c) * n4 + j4] = r;
}

// ---------------------------------------------------------------------------
// Launch
// ---------------------------------------------------------------------------
extern "C" void kernel_launch(void* const* d_in, const int* in_sizes, int n_in,
                              void* d_out, int out_size, void* d_ws, size_t ws_size,
                              hipStream_t stream)
{
    const int N = NN;
    const float* x     = (const float*)d_in[0];
    const float* Wenc1 = (const float*)d_in[1];
    const float* benc1 = (const float*)d_in[2];
    const float* Wenc2 = (const float*)d_in[3];
    const float* benc2 = (const float*)d_in[4];
    const float* Wenc3 = (const float*)d_in[5];
    const float* benc3 = (const float*)d_in[6];
    const float* Wz    = (const float*)d_in[7];
    const float* bz    = (const float*)d_in[8];
    const float* Wk1   = (const float*)d_in[9];
    const float* bk1   = (const float*)d_in[10];
    const float* Wk2   = (const float*)d_in[11];
    const float* bk2   = (const float*)d_in[12];
    const float* Wk3   = (const float*)d_in[13];
    const float* bk3   = (const float*)d_in[14];
    const float* Wk4   = (const float*)d_in[15];
    const float* bk4   = (const float*)d_in[16];
    const float* c_a  = (const float*)d_in[17];
    const float* c_b  = (const float*)d_in[18];
    const float* c_c  = (const float*)d_in[19];
    const float* c_d  = (const float*)d_in[20];
    const float* c_e  = (const float*)d_in[21];
    const float* c_f  = (const float*)d_in[22];
    const float* c_g  = (const float*)d_in[23];
    const float* c_h  = (const float*)d_in[24];
    const float* c_e1 = (const float*)d_in[25];
    const float* c_f1 = (const float*)d_in[26];
    const float* c_g1 = (const float*)d_in[27];
    const float* c_h1 = (const float*)d_in[28];
    const float* c_e2 = (const float*)d_in[29];
    const float* c_f2 = (const float*)d_in[30];
    const float* c_g2 = (const float*)d_in[31];
    const float* c_h2 = (const float*)d_in[32];
    const float* c_e3 = (const float*)d_in[33];
    const float* c_f3 = (const float*)d_in[34];
    const float* c_g3 = (const float*)d_in[35];
    const float* c_h3 = (const float*)d_in[36];
    const float* cluster = (const float*)d_in[37];

    float* out   = (float*)d_out;
    float* xbar  = out + 0;          // 3072*784
    float* k_out = out + 2408448;    // 3072*3072
    float* z_out = out + 11845632;   // 3072*10
    float* h1    = out + 11876352;   // 3072*500
    float* h2    = out + 13412352;   // 3072*500
    float* h3    = out + 14948352;   // 3072*2000
    float* q_out = out + 21092352;   // 3072*10*3072
    float* k22   = out + 115464192;  // 3072*500
    float* k33   = out + 117000192;  // 3072*500
    float* kh1   = out + 118536192;  // 3072*3072
    float* kh2   = out + 127973376;  // 3072*3072
    float* kh3   = out + 137410560;  // 3072*3072
    float* kz    = out + 146847744;  // 3072*3072

    // ---- workspace carve (bf16 hi/lo split buffers), ~163 MB ----
    typedef unsigned short us;
    char* w = (char*)d_ws;
    size_t off = 0;
    auto alloc = [&](size_t bytes) -> void* {
        void* p = w + off;
        off += (bytes + 255) & ~(size_t)255;
        return p;
    };
    us* xs_h  = (us*)alloc((size_t)3072*800*2);  us* xs_l  = (us*)alloc((size_t)3072*800*2);
    us* W1t_h = (us*)alloc((size_t)512*800*2);   us* W1t_l = (us*)alloc((size_t)512*800*2);
    us* h1s_h = (us*)alloc((size_t)3072*512*2);  us* h1s_l = (us*)alloc((size_t)3072*512*2);
    us* W2t_h = (us*)alloc((size_t)512*512*2);   us* W2t_l = (us*)alloc((size_t)512*512*2);
    us* h2s_h = (us*)alloc((size_t)3072*512*2);  us* h2s_l = (us*)alloc((size_t)3072*512*2);
    us* W3t_h = (us*)alloc((size_t)2048*512*2);  us* W3t_l = (us*)alloc((size_t)2048*512*2);
    us* h3s_h = (us*)alloc((size_t)3072*2016*2); us* h3s_l = (us*)alloc((size_t)3072*2016*2);
    us* Wzt_h = (us*)alloc((size_t)128*2016*2);  us* Wzt_l = (us*)alloc((size_t)128*2016*2);
    us* zs_h  = (us*)alloc((size_t)3072*32*2);   us* zs_l  = (us*)alloc((size_t)3072*32*2);
    us* ks_h  = (us*)alloc((size_t)3072*3072*2); us* ks_l  = (us*)alloc((size_t)3072*3072*2);
    us* Wk1t_h= (us*)alloc((size_t)2048*3072*2); us* Wk1t_l= (us*)alloc((size_t)2048*3072*2);
    us* k1s_h = (us*)alloc((size_t)3072*2016*2); us* k1s_l = (us*)alloc((size_t)3072*2016*2);
    us* Wk2t_h= (us*)alloc((size_t)512*2016*2);  us* Wk2t_l= (us*)alloc((size_t)512*2016*2);
    us* k22s_h= (us*)alloc((size_t)3072*512*2);  us* k22s_l= (us*)alloc((size_t)3072*512*2);
    us* Wk3t_h= (us*)alloc((size_t)512*512*2);   us* Wk3t_l= (us*)alloc((size_t)512*512*2);
    us* k33s_h= (us*)alloc((size_t)3072*512*2);  us* k33s_l= (us*)alloc((size_t)3072*512*2);
    us* Wk4t_h= (us*)alloc((size_t)896*512*2);   us* Wk4t_l= (us*)alloc((size_t)896*512*2);
    float* s1 = (float*)alloc(N * sizeof(float));
    float* s2 = (float*)alloc(N * sizeof(float));
    float* s3 = (float*)alloc(N * sizeof(float));
    float* sz = (float*)alloc(N * sizeof(float));
    float* r1 = (float*)alloc(N * sizeof(float));
    float* r2 = (float*)alloc(N * sizeof(float));
    float* r3 = (float*)alloc(N * sizeof(float));
    float* rz = (float*)alloc(N * sizeof(float));

    dim3 blk(256);
    auto gg = [](int m, int n) { return dim3((n + BN - 1) / BN, (m + BM - 1) / BM); };
    dim3 rowgrid(N);
    dim3 cgrid(N / 256, N);
    dim3 dgrid((N + 255) / 256);

    // ---- input splits ----
    split_pad_kernel<<<dim3((3072*800 + 255)/256), blk, 0, stream>>>(x, xs_h, xs_l, 3072, NIN, 800);
    split_transpose_kernel<<<dim3(512/32, 800/32),  blk, 0, stream>>>(Wenc1, W1t_h, W1t_l, NIN, E1D, 800);
    split_transpose_kernel<<<dim3(512/32, 512/32),  blk, 0, stream>>>(Wenc2, W2t_h, W2t_l, E1D, E2D, 512);
    split_transpose_kernel<<<dim3(2048/32, 512/32), blk, 0, stream>>>(Wenc3, W3t_h, W3t_l, E2D, E3D, 512);
    split_transpose_kernel<<<dim3(128/32, 2016/32), blk, 0, stream>>>(Wz, Wzt_h, Wzt_l, E3D, NZD, 2016);
    split_transpose_kernel<<<dim3(2048/32, 3072/32),blk, 0, stream>>>(Wk1, Wk1t_h, Wk1t_l, N, 2000, 3072);
    split_transpose_kernel<<<dim3(512/32, 2016/32), blk, 0, stream>>>(Wk2, Wk2t_h, Wk2t_l, 2000, 500, 2016);
    split_transpose_kernel<<<dim3(512/32, 512/32),  blk, 0, stream>>>(Wk3, Wk3t_h, Wk3t_l, 500, 500, 512);
    split_transpose_kernel<<<dim3(896/32, 512/32),  blk, 0, stream>>>(Wk4, Wk4t_h, Wk4t_l, 500, NIN, 512);

    // ===== encoder layer 1 =====
    gemm3<true ><<<gg(N, E1D), blk, 0, stream>>>(xs_h, xs_l, W1t_h, W1t_l, benc1, h1,
                                                 h1s_h, h1s_l, 512, N, E1D, 800);
    gemm3<false><<<gg(N, N),   blk, 0, stream>>>(h1s_h, h1s_l, h1s_h, h1s_l, nullptr, kh1,
                                                 nullptr, nullptr, 0, N, N, 512);
    diag_kernel<<<dgrid, blk, 0, stream>>>(kh1, s1, N);
    rowsumA_kernel<<<rowgrid, blk, 0, stream>>>(kh1, s1, r1, N);
    combine_kernel<<<cgrid, blk, 0, stream>>>(kh1, s1, r1, c_e1, c_f1, c_g1, c_h1, N);

    // ===== encoder layer 2 =====
    gemm3<true ><<<gg(N, E2D), blk, 0, stream>>>(h1s_h, h1s_l, W2t_h, W2t_l, benc2, h2,
                                                 h2s_h, h2s_l, 512, N, E2D, 512);
    gemm3<false><<<gg(N, N),   blk, 0, stream>>>(h2s_h, h2s_l, h2s_h, h2s_l, nullptr, kh2,
                                                 nullptr, nullptr, 0, N, N, 512);
    diag_kernel<<<dgrid, blk, 0, stream>>>(kh2, s2, N);
    rowsumA_kernel<<<rowgrid, blk, 0, stream>>>(kh2, s2, r2, N);
    combine_kernel<<<cgrid, blk, 0, stream>>>(kh2, s2, r2, c_e2, c_f2, c_g2, c_h2, N);

    // ===== encoder layer 3 =====
    gemm3<true ><<<gg(N, E3D), blk, 0, stream>>>(h2s_h, h2s_l, W3t_h, W3t_l, benc3, h3,
                                                 h3s_h, h3s_l, 2016, N, E3D, 512);
    gemm3<false><<<gg(N, N),   blk, 0, stream>>>(h3s_h, h3s_l, h3s_h, h3s_l, nullptr, kh3,
                                                 nullptr, nullptr, 0, N, N, 2016);
    diag_kernel<<<dgrid, blk, 0, stream>>>(kh3, s3, N);
    rowsumA_kernel<<<rowgrid, blk, 0, stream>>>(kh3, s3, r3, N);
    combine_kernel<<<cgrid, blk, 0, stream>>>(kh3, s3, r3, c_e3, c_f3, c_g3, c_h3, N);

    // ===== latent z =====
    gemm3<true ><<<gg(N, NZD), blk, 0, stream>>>(h3s_h, h3s_l, Wzt_h, Wzt_l, bz, z_out,
                                                 zs_h, zs_l, 32, N, NZD, 2016);
    gemm3<false><<<gg(N, N),   blk, 0, stream>>>(zs_h, zs_l, zs_h, zs_l, nullptr, kz,
                                                 nullptr, nullptr, 0, N, N, 32);
    diag_kernel<<<dgrid, blk, 0, stream>>>(kz, sz, N);
    rowsumA_kernel<<<rowgrid, blk, 0, stream>>>(kz, sz, rz, N);
    combine_kernel<<<cgrid, blk, 0, stream>>>(kz, sz, rz, c_e, c_f, c_g, c_h, N);

    // ===== k = a*kh1 + b*kh2 + c*kh3 + d*kz  (+ split) =====
    {
        int n4 = N * N / 4;
        kcombine_kernel<<<dim3((n4 + 255) / 256), blk, 0, stream>>>(
            (const float4*)kh1, (const float4*)kh2, (const float4*)kh3, (const float4*)kz,
            (const float4*)c_a, (const float4*)c_b, (const float4*)c_c, (const float4*)c_d,
            (float4*)k_out, (ushort4*)ks_h, (ushort4*)ks_l, n4);
    }

    // ===== decoder chain =====
    gemm3<true ><<<gg(N, 2000), blk, 0, stream>>>(ks_h, ks_l, Wk1t_h, Wk1t_l, bk1, nullptr,
                                                  k1s_h, k1s_l, 2016, N, 2000, 3072);
    gemm3<true ><<<gg(N, 500),  blk, 0, stream>>>(k1s_h, k1s_l, Wk2t_h, Wk2t_l, bk2, k22,
                                                  k22s_h, k22s_l, 512, N, 500, 2016);
    gemm3<true ><<<gg(N, 500),  blk, 0, stream>>>(k22s_h, k22s_l, Wk3t_h, Wk3t_l, bk3, k33,
                                                  k33s_h, k33s_l, 512, N, 500, 512);
    gemm3<false><<<gg(N, NIN),  blk, 0, stream>>>(k33s_h, k33s_l, Wk4t_h, Wk4t_l, bk4, xbar,
                                                  nullptr, nullptr, 0, N, NIN, 512);

    // ===== q = k[:,None,:] - cluster[None,:,:] =====
    {
        int per_i = NCD * N / 4;
        q_kernel<<<dim3(per_i / 256, N), blk, 0, stream>>>(
            (const float4*)k_out, (const float4*)cluster, (float4*)q_out, N, NCD);
    }
}